// Round 7
// baseline (226.769 us; speedup 1.0000x reference)
//
#include <hip/hip_runtime.h>
#include <hip/hip_bf16.h>

#define B_   16
#define CIN  256
#define CO   128
#define HW   4096

typedef __attribute__((ext_vector_type(8))) short short8;
typedef __attribute__((ext_vector_type(4))) float f32x4;
typedef __attribute__((ext_vector_type(4))) unsigned u32x4;

__device__ __forceinline__ short f32_to_bf16_rne(float f) {
    union { float f; unsigned u; } v; v.f = f;
    unsigned u = v.u;
    u += 0x7fffu + ((u >> 16) & 1u);
    return (short)(u >> 16);
}

__device__ __forceinline__ unsigned pack_bf16(float lo, float hi) {
    return (unsigned)(unsigned short)f32_to_bf16_rne(lo) |
           ((unsigned)(unsigned short)f32_to_bf16_rne(hi) << 16);
}

// ---------------------------------------------------------------------------
// Weight pre-convert: wbf[0][co][ci] = bf16(theta_w), wbf[1][co][ci] = bf16(phi_w)
// ---------------------------------------------------------------------------
__global__ __launch_bounds__(256) void wconv_kernel(
    const float* __restrict__ tw, const float* __restrict__ pw,
    short* __restrict__ wbf)
{
    const int idx = blockIdx.x * 256 + threadIdx.x;     // 0 .. 2*CO*CIN-1
    const float v = (idx < CO * CIN) ? tw[idx] : pw[idx - CO * CIN];
    wbf[idx] = f32_to_bf16_rne(v);
}

// ---------------------------------------------------------------------------
// Projection v5: out_T[b][i][co] = sum_ci x[b][ci][i] * w[co][ci] + bias[co]
// grid 2048, block 256 (4 waves), XCD-swizzled by batch, itile fastest
// (keeps round-5's camping fix).
// v5 vs v4: WIDE LOADS. v4 issued 64 scalar dword loads/thread at VGPR=56 --
// zero register slack, loads drained in serialized batches (block lifetime
// 20us for 80KB => load-convoy-bound, all pipes <11%). v5: each thread loads
// 8x float4 (8 ci-rows x 4 consecutive i, 16B/lane coalesced), cvt+pack in
// regs, 4x ds_write_b128 into [64 i][128 ci] bf16 tile, 16B-chunk XOR
// swizzle ck^(t&15) (order-preserving => MFMA k-order intact; <=4-way
// conflicts, 1.58x on a non-critical pipe). 2 K-chunks of 128, LDS+wf
// double-buffered. ~150 VGPR -> compiler can keep all 8 loads in flight.
// ---------------------------------------------------------------------------
__global__ __launch_bounds__(256, 3) void proj_kernel(
    const float* __restrict__ xg, const float* __restrict__ xq,
    const float* __restrict__ tb, const float* __restrict__ pb,
    const short* __restrict__ wbf,
    short* __restrict__ tT, short* __restrict__ pT)
{
    const int n     = blockIdx.x;
    const int xcd   = n & 7;
    const int q     = n >> 3;            // 0..255
    const int itile = q & 63;            // FASTEST: spreads addr bits [13:8]
    const int rr    = q >> 6;            // 0..3
    const int which = rr & 1;
    const int b     = xcd + 8 * (rr >> 1);

    const float* x    = which ? xq : xg;
    const float* bias = which ? pb : tb;
    const short* wb   = wbf + which * CO * CIN;
    short*       out  = which ? pT : tT;

    const int i0   = itile * 64;
    const int tid  = threadIdx.x;
    const int lane = tid & 63;
    const int wv   = tid >> 6;          // wave 0..3 -> co range [wv*32, wv*32+32)
    const int nrow = lane & 15;
    const int quad = lane >> 4;

    const int iq   = (tid & 15) * 4;    // this thread's 4-i group
    const int g    = tid >> 4;          // this thread's 8-ci group (0..15)
    const int swz  = tid & 15;          // write swizzle = (i>>2)&15 = iq>>2

    __shared__ __align__(16) short xT[2][64][128];  // [buf][i][ci] bf16, 32 KB

    f32x4 acc[4][2] = {};               // 4 m-subtiles (i) x 2 n-subtiles (co)

    float bias_v[2];
    bias_v[0] = bias[wv * 32 + 0  + nrow];
    bias_v[1] = bias[wv * 32 + 16 + nrow];

    const float* xb = x + (long)b * CIN * HW + i0;

    // ---- staging: 8 x float4 per thread per chunk (rows g*8..g*8+7, i iq..iq+3)
    float4 lv[8];
    auto stage_load = [&](int c) {
        const float* src = xb + (long)(c * 128 + g * 8) * HW + iq;
        #pragma unroll
        for (int r = 0; r < 8; r++)
            lv[r] = *(const float4*)(src + (long)r * HW);
    };
    auto stage_write = [&](int buf) {
        const int ck = (g ^ swz) * 8;   // swizzled 16B chunk (8 shorts)
        #pragma unroll
        for (int k = 0; k < 4; k++) {   // i = iq + k
            u32x4 d;
            const float* f = (const float*)lv;
            #pragma unroll
            for (int p = 0; p < 4; p++)
                d[p] = pack_bf16(f[(2 * p) * 4 + k], f[(2 * p + 1) * 4 + k]);
            *(u32x4*)&xT[buf][iq + k][ck] = d;
        }
    };

    // ---- weight fragments: double-buffered per chunk (2 x 32 VGPR)
    short8 wf[2][4][2];                 // [buf][ks][nt]
    auto wload = [&](int c, int buf) {
        #pragma unroll
        for (int ks = 0; ks < 4; ks++)
            #pragma unroll
            for (int nt = 0; nt < 2; nt++)
                wf[buf][ks][nt] = *(const short8*)(
                    wb + (wv * 32 + nt * 16 + nrow) * CIN + c * 128 + ks * 32 + quad * 8);
    };

    auto compute = [&](int buf) {
        #pragma unroll
        for (int ks = 0; ks < 4; ks++)
            #pragma unroll
            for (int mt = 0; mt < 4; mt++) {
                const int row = mt * 16 + nrow;
                const int ck  = ((ks * 4 + quad) ^ ((row >> 2) & 15)) * 8;
                const short8 a = *(const short8*)&xT[buf][row][ck];
                acc[mt][0] = __builtin_amdgcn_mfma_f32_16x16x32_bf16(a, wf[buf][ks][0], acc[mt][0], 0, 0, 0);
                acc[mt][1] = __builtin_amdgcn_mfma_f32_16x16x32_bf16(a, wf[buf][ks][1], acc[mt][1], 0, 0, 0);
            }
    };

    wload(0, 0);
    stage_load(0);
    stage_write(0);
    __syncthreads();
    stage_load(1);                       // 8 loads in flight across compute(0)
    wload(1, 1);
    compute(0);
    stage_write(1);
    __syncthreads();
    compute(1);

    // ---- store: D layout col = lane&15 (co), row = quad*4 + reg (i)
    #pragma unroll
    for (int mt = 0; mt < 4; mt++)
        #pragma unroll
        for (int nt = 0; nt < 2; nt++) {
            const int co = wv * 32 + nt * 16 + nrow;
            #pragma unroll
            for (int r = 0; r < 4; r++) {
                const int il = mt * 16 + quad * 4 + r;
                out[((long)b * HW + i0 + il) * CO + co] =
                    f32_to_bf16_rne(acc[mt][nt][r] + bias_v[nt]);
            }
        }
}

// ---------------------------------------------------------------------------
// Max-GEMM v3: pmax[jq][b][i] = max_{j in quarter jq} sum_c tT[b][i][c]*pT[b][j][c]
// (unchanged from round 6: grid 512, 2 blocks/CU, 128 i per wave)
// ---------------------------------------------------------------------------
__global__ __launch_bounds__(256, 2) void maxgemm_kernel(
    const short* __restrict__ tT, const short* __restrict__ pT,
    float* __restrict__ pmax)
{
    const int n     = blockIdx.x;        // 0..511
    const int b     = (n & 7) + 8 * ((n >> 3) & 1);
    const int mm    = n >> 4;            // 0..31
    const int itile = mm & 7;            // 0..7
    const int jq    = mm >> 3;           // 0..3
    const int i0    = itile * 512;
    const int j0    = jq * 1024;
    const int tid   = threadIdx.x;
    const int lane  = tid & 63;
    const int wv    = tid >> 6;
    const int nrow  = lane & 15;
    const int quad  = lane >> 4;

    __shared__ short bT[2][64][128];     // 32 KB, unpadded, XOR-swizzled chunks

    // ---- loop-invariant A fragments: this wave's 128 i x 128 c (128 VGPRs)
    short8 afrag[8][4];
    {
        const short* ta = tT + ((long)b * HW + i0 + wv * 128) * CO;
        #pragma unroll
        for (int mt = 0; mt < 8; mt++)
            #pragma unroll
            for (int ks = 0; ks < 4; ks++)
                afrag[mt][ks] = *(const short8*)(ta + (mt * 16 + nrow) * CO + ks * 32 + quad * 8);
    }

    const short* pb2 = pT + (long)b * HW * CO + (long)j0 * CO;
    const int sc8 = tid & 15;            // 16B chunk within row
    const int sj0 = tid >> 4;            // 0..15

    short8 sreg[4];
    auto stage_load = [&](int jt) {      // global -> regs (coalesced 256B segs)
        const short* src = pb2 + (long)jt * 64 * CO;
        #pragma unroll
        for (int r = 0; r < 4; r++)
            sreg[r] = *(const short8*)(src + (sj0 + r * 16) * CO + sc8 * 8);
    };
    auto stage_write = [&](int buf) {    // regs -> LDS, swizzled chunk
        #pragma unroll
        for (int r = 0; r < 4; r++) {
            const int j  = sj0 + r * 16;
            const int c8 = sc8 ^ (j & 7);
            *(short8*)&bT[buf][j][c8 * 8] = sreg[r];
        }
    };

    f32x4 vmax[8];
    #pragma unroll
    for (int mt = 0; mt < 8; mt++)
        vmax[mt] = (f32x4){-1e30f, -1e30f, -1e30f, -1e30f};

    const f32x4 kz = {0.f, 0.f, 0.f, 0.f};   // hoisted MFMA C operand

    auto compute = [&](int buf) {
        #pragma unroll
        for (int np = 0; np < 2; np++) {      // nt pairs: j groups np*32, np*32+16
            short8 bf0[4], bf1[4];
            const int ja = np * 32 + nrow;
            const int jb = ja + 16;
            #pragma unroll
            for (int ks = 0; ks < 4; ks++) {
                bf0[ks] = *(const short8*)&bT[buf][ja][(((ks * 4 + quad) ^ (ja & 7)) * 8)];
                bf1[ks] = *(const short8*)&bT[buf][jb][(((ks * 4 + quad) ^ (jb & 7)) * 8)];
            }
            #pragma unroll
            for (int mt = 0; mt < 8; mt++) {
                f32x4 a0 = __builtin_amdgcn_mfma_f32_16x16x32_bf16(afrag[mt][0], bf0[0], kz, 0, 0, 0);
                f32x4 a1 = __builtin_amdgcn_mfma_f32_16x16x32_bf16(afrag[mt][0], bf1[0], kz, 0, 0, 0);
                #pragma unroll
                for (int ks = 1; ks < 4; ks++) {
                    a0 = __builtin_amdgcn_mfma_f32_16x16x32_bf16(afrag[mt][ks], bf0[ks], a0, 0, 0, 0);
                    a1 = __builtin_amdgcn_mfma_f32_16x16x32_bf16(afrag[mt][ks], bf1[ks], a1, 0, 0, 0);
                }
                #pragma unroll
                for (int r = 0; r < 4; r++)
                    vmax[mt][r] = fmaxf(fmaxf(a0[r], a1[r]), vmax[mt][r]);  // v_max3
            }
        }
    };

    stage_load(0);
    stage_write(0);
    for (int jt = 0; jt < 16; jt++) {
        __syncthreads();
        if (jt < 15) stage_load(jt + 1);     // prefetch overlaps MFMA below
        compute(jt & 1);
        if (jt < 15) stage_write((jt + 1) & 1);
    }

    // ---- reduce max over 16 j-columns (lane bits 0-3); each wave owns its 128 i
    #pragma unroll
    for (int mt = 0; mt < 8; mt++)
        #pragma unroll
        for (int r = 0; r < 4; r++) {
            float v = vmax[mt][r];
            #pragma unroll
            for (int m = 8; m >= 1; m >>= 1)
                v = fmaxf(v, __shfl_xor(v, m, 64));
            vmax[mt][r] = v;
        }

    if (nrow == 0) {
        float* pm = pmax + (size_t)jq * (B_ * HW) + (size_t)b * HW + i0 + wv * 128;
        #pragma unroll
        for (int mt = 0; mt < 8; mt++)
            #pragma unroll
            for (int r = 0; r < 4; r++)
                pm[mt * 16 + quad * 4 + r] = vmax[mt][r];
    }
}

// ---------------------------------------------------------------------------
// Combine the four j-quarter partial maxes, scale, sigmoid. 65536 outputs.
// ---------------------------------------------------------------------------
__global__ __launch_bounds__(256) void combine_kernel(
    const float* __restrict__ pmax, float* __restrict__ out)
{
    const int idx = blockIdx.x * 256 + threadIdx.x;   // < B_*HW
    float v = pmax[idx];
    #pragma unroll
    for (int p = 1; p < 4; p++)
        v = fmaxf(v, pmax[idx + p * (B_ * HW)]);
    v *= (1.0f / (float)HW);
    out[idx] = 1.0f / (1.0f + __expf(-v));
}

extern "C" void kernel_launch(void* const* d_in, const int* in_sizes, int n_in,
                              void* d_out, int out_size, void* d_ws, size_t ws_size,
                              hipStream_t stream) {
    const float* xg = (const float*)d_in[0];
    const float* xq = (const float*)d_in[1];
    const float* tw = (const float*)d_in[2];
    const float* tb = (const float*)d_in[3];
    const float* pw = (const float*)d_in[4];
    const float* pb = (const float*)d_in[5];
    float* out = (float*)d_out;

    short* tT  = (short*)d_ws;                         // [B][HW][CO] bf16, 16.78 MB
    short* pT  = tT + (size_t)B_ * HW * CO;            // [B][HW][CO] bf16, 16.78 MB
    short* wbf = pT + (size_t)B_ * HW * CO;            // [2][CO][CIN] bf16, 131 KB
    float* pmax = (float*)(wbf + 2 * CO * CIN);        // [4][B][HW] f32, 1.05 MB

    wconv_kernel<<<(2 * CO * CIN) / 256, 256, 0, stream>>>(tw, pw, wbf);
    proj_kernel<<<B_ * (HW / 64) * 2, 256, 0, stream>>>(xg, xq, tb, pb, wbf, tT, pT);
    maxgemm_kernel<<<B_ * (HW / 512) * 4, 256, 0, stream>>>(tT, pT, pmax);
    combine_kernel<<<(B_ * HW) / 256, 256, 0, stream>>>(pmax, out);
}

// Round 8
// 220.703 us; speedup vs baseline: 1.0275x; 1.0275x over previous
//
#include <hip/hip_runtime.h>
#include <hip/hip_bf16.h>

#define B_   16
#define CIN  256
#define CO   128
#define HW   4096

typedef __attribute__((ext_vector_type(8))) short short8;
typedef __attribute__((ext_vector_type(4))) float f32x4;
typedef __attribute__((ext_vector_type(4))) unsigned u32x4;

__device__ __forceinline__ short f32_to_bf16_rne(float f) {
    union { float f; unsigned u; } v; v.f = f;
    unsigned u = v.u;
    u += 0x7fffu + ((u >> 16) & 1u);
    return (short)(u >> 16);
}

__device__ __forceinline__ unsigned pack_bf16(float lo, float hi) {
    return (unsigned)(unsigned short)f32_to_bf16_rne(lo) |
           ((unsigned)(unsigned short)f32_to_bf16_rne(hi) << 16);
}

// HBM->LDS direct DMA, 16B per lane. LDS dest = wave-uniform base + lane*16;
// global src is per-lane (so swizzles are done by pre-swizzling the source).
__device__ __forceinline__ void gload16(const void* g, void* l) {
    __builtin_amdgcn_global_load_lds(
        (const __attribute__((address_space(1))) void*)g,
        (__attribute__((address_space(3))) void*)l, 16, 0, 0);
}

// ---------------------------------------------------------------------------
// Weight pre-convert: wbf[0][co][ci] = bf16(theta_w), wbf[1][co][ci] = bf16(phi_w)
// ---------------------------------------------------------------------------
__global__ __launch_bounds__(256) void wconv_kernel(
    const float* __restrict__ tw, const float* __restrict__ pw,
    short* __restrict__ wbf)
{
    const int idx = blockIdx.x * 256 + threadIdx.x;     // 0 .. 2*CO*CIN-1
    const float v = (idx < CO * CIN) ? tw[idx] : pw[idx - CO * CIN];
    wbf[idx] = f32_to_bf16_rne(v);
}

// ---------------------------------------------------------------------------
// Projection v6: out_T[b][i][co] = sum_ci x[b][ci][i] * w[co][ci] + bias[co]
// grid 2048 (itile fastest: keeps round-5 camping fix), block 256 (4 waves).
// v6 vs v5: STAGING VIA global_load_lds DMA (zero VGPR, all loads in flight,
// drain only at barrier). v5's compiler collapsed reg-staged pipeline to
// VGPR=52 => 1 load in flight => 1.3 TB/s. v6:
//   - x staged AS-IS (f32 [ci][i]) into padded [16][4ci][64i] tile
//     (+16B/group pad -> 2-way banks = free on frag gathers)
//   - wave owns 16 i x ALL 128 co (M-split: A-frag gather paid once, not x4)
//   - A-frag = 8x ds_read_b32 + in-reg bf16 pack (transpose at read time)
//   - w DMA-staged per chunk [co][ci] bf16, source-pre-swizzled ck^(co&7),
//     shared by all waves (no 64-VGPR wf array, no per-wave L2 re-reads)
// BK=64, 4 chunks, dbuf; issue DMA(c+1) -> compute(c) -> barrier.
// LDS 65 KB -> 2 blocks/CU; ~100 VGPR.
// ---------------------------------------------------------------------------
__global__ __launch_bounds__(256, 2) void proj_kernel(
    const float* __restrict__ xg, const float* __restrict__ xq,
    const float* __restrict__ tb, const float* __restrict__ pb,
    const short* __restrict__ wbf,
    short* __restrict__ tT, short* __restrict__ pT)
{
    const int n     = blockIdx.x;
    const int xcd   = n & 7;
    const int q     = n >> 3;            // 0..255
    const int itile = q & 63;            // FASTEST: spreads addr bits [13:8]
    const int rr    = q >> 6;            // 0..3
    const int which = rr & 1;
    const int b     = xcd + 8 * (rr >> 1);

    const float* x    = which ? xq : xg;
    const float* bias = which ? pb : tb;
    const short* wb   = wbf + which * CO * CIN;
    short*       out  = which ? pT : tT;

    const int i0   = itile * 64;
    const int tid  = threadIdx.x;
    const int lane = tid & 63;
    const int wv   = tid >> 6;          // wave 0..3 -> i range [wv*16, wv*16+16)
    const int nrow = lane & 15;
    const int quad = lane >> 4;

    __shared__ __align__(16) float ftile[2][16][260];   // x chunk [g][(ci&3)*64+i], 33.3 KB
    __shared__ __align__(16) short wtile[2][128][64];   // w chunk [co][ci swz], 32 KB

    // ---- DMA: x chunk (64 ci x 64 i f32 = 16 KB), 16 groups of 4 ci rows
    const float* xb = x + (long)b * CIN * HW + i0;
    auto stage_x = [&](int c, int buf) {
        #pragma unroll
        for (int s = 0; s < 4; s++) {
            const int g = wv * 4 + s;
            const float* gsrc = xb + (long)(c * 64 + g * 4 + (lane >> 4)) * HW + (lane & 15) * 4;
            gload16(gsrc, &ftile[buf][g][0]);
        }
    };
    // ---- DMA: w chunk (128 co x 64 ci bf16 = 16 KB), source-pre-swizzled
    auto stage_w = [&](int c, int buf) {
        #pragma unroll
        for (int s = 0; s < 4; s++) {
            const int g  = wv * 4 + s;              // co-group of 8 rows
            const int co = g * 8 + (lane >> 3);
            const int ck = (lane & 7) ^ (co & 7);   // src ci-chunk (involution)
            const short* gsrc = wb + (long)co * CIN + c * 64 + ck * 8;
            gload16(gsrc, &wtile[buf][g * 8][0]);
        }
    };

    f32x4 acc[8] = {};                  // 8 co-subtiles x (4 i) accumulator

    float bias_v[8];
    #pragma unroll
    for (int nt = 0; nt < 8; nt++)
        bias_v[nt] = bias[nt * 16 + nrow];

    auto compute = [&](int buf) {
        #pragma unroll
        for (int ks = 0; ks < 2; ks++) {
            // A-frag gather: 8 f32 (ci = ks*32+quad*8+r, i = wv*16+nrow), 2-way banks
            float af[8];
            #pragma unroll
            for (int r = 0; r < 8; r++) {
                const int ci = ks * 32 + quad * 8 + r;
                af[r] = ftile[buf][ci >> 2][(ci & 3) * 64 + wv * 16 + nrow];
            }
            u32x4 ap;
            #pragma unroll
            for (int p = 0; p < 4; p++)
                ap[p] = pack_bf16(af[2 * p], af[2 * p + 1]);
            const short8 a = *(const short8*)&ap;
            #pragma unroll
            for (int nt = 0; nt < 8; nt++) {
                const int co = nt * 16 + nrow;
                const int sw = (ks * 4 + quad) ^ (co & 7);
                const short8 bw = *(const short8*)&wtile[buf][co][sw * 8];
                acc[nt] = __builtin_amdgcn_mfma_f32_16x16x32_bf16(a, bw, acc[nt], 0, 0, 0);
            }
        }
    };

    stage_x(0, 0);
    stage_w(0, 0);
    __syncthreads();                    // drain chunk-0 DMA
    #pragma unroll
    for (int c = 0; c < 4; c++) {
        if (c < 3) { stage_x(c + 1, (c + 1) & 1); stage_w(c + 1, (c + 1) & 1); }
        compute(c & 1);                 // overlaps with next chunk's DMA
        __syncthreads();                // drain DMA(c+1), release buf for c+2
    }

    // ---- store: D col = lane&15 (co sub), row = quad*4 + r (i sub)
    #pragma unroll
    for (int nt = 0; nt < 8; nt++) {
        const int co = nt * 16 + nrow;
        #pragma unroll
        for (int r = 0; r < 4; r++) {
            const int il = wv * 16 + quad * 4 + r;
            out[((long)b * HW + i0 + il) * CO + co] =
                f32_to_bf16_rne(acc[nt][r] + bias_v[nt]);
        }
    }
}

// ---------------------------------------------------------------------------
// Max-GEMM v3: pmax[jq][b][i] = max_{j in quarter jq} sum_c tT[b][i][c]*pT[b][j][c]
// (unchanged from round 6: grid 512, 2 blocks/CU, 128 i per wave)
// ---------------------------------------------------------------------------
__global__ __launch_bounds__(256, 2) void maxgemm_kernel(
    const short* __restrict__ tT, const short* __restrict__ pT,
    float* __restrict__ pmax)
{
    const int n     = blockIdx.x;        // 0..511
    const int b     = (n & 7) + 8 * ((n >> 3) & 1);
    const int mm    = n >> 4;            // 0..31
    const int itile = mm & 7;            // 0..7
    const int jq    = mm >> 3;           // 0..3
    const int i0    = itile * 512;
    const int j0    = jq * 1024;
    const int tid   = threadIdx.x;
    const int lane  = tid & 63;
    const int wv    = tid >> 6;
    const int nrow  = lane & 15;
    const int quad  = lane >> 4;

    __shared__ short bT[2][64][128];     // 32 KB, unpadded, XOR-swizzled chunks

    // ---- loop-invariant A fragments: this wave's 128 i x 128 c (128 VGPRs)
    short8 afrag[8][4];
    {
        const short* ta = tT + ((long)b * HW + i0 + wv * 128) * CO;
        #pragma unroll
        for (int mt = 0; mt < 8; mt++)
            #pragma unroll
            for (int ks = 0; ks < 4; ks++)
                afrag[mt][ks] = *(const short8*)(ta + (mt * 16 + nrow) * CO + ks * 32 + quad * 8);
    }

    const short* pb2 = pT + (long)b * HW * CO + (long)j0 * CO;
    const int sc8 = tid & 15;            // 16B chunk within row
    const int sj0 = tid >> 4;            // 0..15

    short8 sreg[4];
    auto stage_load = [&](int jt) {      // global -> regs (coalesced 256B segs)
        const short* src = pb2 + (long)jt * 64 * CO;
        #pragma unroll
        for (int r = 0; r < 4; r++)
            sreg[r] = *(const short8*)(src + (sj0 + r * 16) * CO + sc8 * 8);
    };
    auto stage_write = [&](int buf) {    // regs -> LDS, swizzled chunk
        #pragma unroll
        for (int r = 0; r < 4; r++) {
            const int j  = sj0 + r * 16;
            const int c8 = sc8 ^ (j & 7);
            *(short8*)&bT[buf][j][c8 * 8] = sreg[r];
        }
    };

    f32x4 vmax[8];
    #pragma unroll
    for (int mt = 0; mt < 8; mt++)
        vmax[mt] = (f32x4){-1e30f, -1e30f, -1e30f, -1e30f};

    const f32x4 kz = {0.f, 0.f, 0.f, 0.f};   // hoisted MFMA C operand

    auto compute = [&](int buf) {
        #pragma unroll
        for (int np = 0; np < 2; np++) {      // nt pairs: j groups np*32, np*32+16
            short8 bf0[4], bf1[4];
            const int ja = np * 32 + nrow;
            const int jb = ja + 16;
            #pragma unroll
            for (int ks = 0; ks < 4; ks++) {
                bf0[ks] = *(const short8*)&bT[buf][ja][(((ks * 4 + quad) ^ (ja & 7)) * 8)];
                bf1[ks] = *(const short8*)&bT[buf][jb][(((ks * 4 + quad) ^ (jb & 7)) * 8)];
            }
            #pragma unroll
            for (int mt = 0; mt < 8; mt++) {
                f32x4 a0 = __builtin_amdgcn_mfma_f32_16x16x32_bf16(afrag[mt][0], bf0[0], kz, 0, 0, 0);
                f32x4 a1 = __builtin_amdgcn_mfma_f32_16x16x32_bf16(afrag[mt][0], bf1[0], kz, 0, 0, 0);
                #pragma unroll
                for (int ks = 1; ks < 4; ks++) {
                    a0 = __builtin_amdgcn_mfma_f32_16x16x32_bf16(afrag[mt][ks], bf0[ks], a0, 0, 0, 0);
                    a1 = __builtin_amdgcn_mfma_f32_16x16x32_bf16(afrag[mt][ks], bf1[ks], a1, 0, 0, 0);
                }
                #pragma unroll
                for (int r = 0; r < 4; r++)
                    vmax[mt][r] = fmaxf(fmaxf(a0[r], a1[r]), vmax[mt][r]);  // v_max3
            }
        }
    };

    stage_load(0);
    stage_write(0);
    for (int jt = 0; jt < 16; jt++) {
        __syncthreads();
        if (jt < 15) stage_load(jt + 1);     // prefetch overlaps MFMA below
        compute(jt & 1);
        if (jt < 15) stage_write((jt + 1) & 1);
    }

    // ---- reduce max over 16 j-columns (lane bits 0-3); each wave owns its 128 i
    #pragma unroll
    for (int mt = 0; mt < 8; mt++)
        #pragma unroll
        for (int r = 0; r < 4; r++) {
            float v = vmax[mt][r];
            #pragma unroll
            for (int m = 8; m >= 1; m >>= 1)
                v = fmaxf(v, __shfl_xor(v, m, 64));
            vmax[mt][r] = v;
        }

    if (nrow == 0) {
        float* pm = pmax + (size_t)jq * (B_ * HW) + (size_t)b * HW + i0 + wv * 128;
        #pragma unroll
        for (int mt = 0; mt < 8; mt++)
            #pragma unroll
            for (int r = 0; r < 4; r++)
                pm[mt * 16 + quad * 4 + r] = vmax[mt][r];
    }
}

// ---------------------------------------------------------------------------
// Combine the four j-quarter partial maxes, scale, sigmoid. 65536 outputs.
// ---------------------------------------------------------------------------
__global__ __launch_bounds__(256) void combine_kernel(
    const float* __restrict__ pmax, float* __restrict__ out)
{
    const int idx = blockIdx.x * 256 + threadIdx.x;   // < B_*HW
    float v = pmax[idx];
    #pragma unroll
    for (int p = 1; p < 4; p++)
        v = fmaxf(v, pmax[idx + p * (B_ * HW)]);
    v *= (1.0f / (float)HW);
    out[idx] = 1.0f / (1.0f + __expf(-v));
}

extern "C" void kernel_launch(void* const* d_in, const int* in_sizes, int n_in,
                              void* d_out, int out_size, void* d_ws, size_t ws_size,
                              hipStream_t stream) {
    const float* xg = (const float*)d_in[0];
    const float* xq = (const float*)d_in[1];
    const float* tw = (const float*)d_in[2];
    const float* tb = (const float*)d_in[3];
    const float* pw = (const float*)d_in[4];
    const float* pb = (const float*)d_in[5];
    float* out = (float*)d_out;

    short* tT  = (short*)d_ws;                         // [B][HW][CO] bf16, 16.78 MB
    short* pT  = tT + (size_t)B_ * HW * CO;            // [B][HW][CO] bf16, 16.78 MB
    short* wbf = pT + (size_t)B_ * HW * CO;            // [2][CO][CIN] bf16, 131 KB
    float* pmax = (float*)(wbf + 2 * CO * CIN);        // [4][B][HW] f32, 1.05 MB

    wconv_kernel<<<(2 * CO * CIN) / 256, 256, 0, stream>>>(tw, pw, wbf);
    proj_kernel<<<B_ * (HW / 64) * 2, 256, 0, stream>>>(xg, xq, tb, pb, wbf, tT, pT);
    maxgemm_kernel<<<B_ * (HW / 512) * 4, 256, 0, stream>>>(tT, pT, pmax);
    combine_kernel<<<(B_ * HW) / 256, 256, 0, stream>>>(pmax, out);
}